// Round 2
// baseline (323.573 us; speedup 1.0000x reference)
//
#include <hip/hip_runtime.h>
#include <hip/hip_bf16.h>

// Inputs/outputs are FLOAT32 (reference dtypes). Internal compute: bf16 MFMA
// with split-precision (hi/lo) projections for accuracy; tolerance is
// 0.02 * max|ref| ~= 0.028 absolute.
typedef __bf16 bf16;
typedef __bf16 bf16x8 __attribute__((ext_vector_type(8)));
typedef float  f32x4  __attribute__((ext_vector_type(4)));

#define DEVINL __device__ __forceinline__

DEVINL void gll16(const void* g, void* l) {
  __builtin_amdgcn_global_load_lds(
      (const __attribute__((address_space(1))) unsigned int*)g,
      (__attribute__((address_space(3))) unsigned int*)l, 16, 0, 0);
}

// ---------------------------------------------------------------------------
// Weight prep: W[k][n] (256x256 f32) -> Wt_hi[n][k], Wt_lo[n][k] (bf16).
// m: 0=Wq, 1=Wk, 2=Wv (k/v concat into wtkv[512][256]), 3=Wo.
// ---------------------------------------------------------------------------
__global__ void k_prep(const float* __restrict__ Wq, const float* __restrict__ Wk,
                       const float* __restrict__ Wv, const float* __restrict__ Wo,
                       bf16* __restrict__ wtq_h, bf16* __restrict__ wtq_l,
                       bf16* __restrict__ wtkv_h, bf16* __restrict__ wtkv_l,
                       bf16* __restrict__ wto_h, bf16* __restrict__ wto_l) {
  const int k = blockIdx.x;
  const int n = threadIdx.x;
  const int m = blockIdx.y;
  const float* src = (m == 0) ? Wq : (m == 1) ? Wk : (m == 2) ? Wv : Wo;
  bf16* dh = (m == 0) ? wtq_h : (m == 3) ? wto_h : (m == 1) ? wtkv_h : (wtkv_h + 256 * 256);
  bf16* dl = (m == 0) ? wtq_l : (m == 3) ? wto_l : (m == 1) ? wtkv_l : (wtkv_l + 256 * 256);
  const float v = src[k * 256 + n];
  const bf16 h = (bf16)v;
  dh[n * 256 + k] = h;
  dl[n * 256 + k] = (bf16)(v - (float)h);
}

// ---------------------------------------------------------------------------
// Split-precision GEMM: out[m][n] = sum_k A[m][k]*W[k][n] + bias[n]
//   A: [65536][256] f32 (ABF16=false) or bf16 (ABF16=true)
//   W given transposed+split: Wt_hi/Wt_lo [Nn][256] bf16.
//   Terms: Ah*Wh + Ah*Wl (+ Al*Wh if !ABF16).
// 128x128 tile, BK=32, 4 waves, 4x4 MFMA 16x16x32 per wave.
// Columns n>=256 go to out1/bias1 (for fused [Wk|Wv] projection).
// ---------------------------------------------------------------------------
template <bool ABF16, bool OUTF32>
__global__ __launch_bounds__(256) void k_gemm3(
    const void* __restrict__ Aptr,
    const bf16* __restrict__ Wth, const bf16* __restrict__ Wtl,
    const float* __restrict__ bias0, const float* __restrict__ bias1,
    void* __restrict__ out0, void* __restrict__ out1) {
  __shared__ __align__(16) bf16 Ash[128 * 32];
  __shared__ __align__(16) bf16 Asl[128 * 32];
  __shared__ __align__(16) bf16 Bsh[128 * 32];
  __shared__ __align__(16) bf16 Bsl[128 * 32];

  const int tid = threadIdx.x;
  const int lane = tid & 63;
  const int wave = tid >> 6;
  const int m0 = blockIdx.x * 128;
  const int n0 = blockIdx.y * 128;
  const int mw = (wave >> 1) * 64;
  const int nw = (wave & 1) * 64;
  const int lm = lane & 15;
  const int lq = lane >> 4;

  f32x4 acc[4][4];
#pragma unroll
  for (int i = 0; i < 4; ++i)
#pragma unroll
    for (int j = 0; j < 4; ++j) acc[i][j] = (f32x4)0.0f;

  // B staging chunks (16B each, 512 chunks over an 8KB tile)
  const int c0 = wave * 128 + lane;
  const int c1 = c0 + 64;
  const int rB0 = c0 >> 2, oB0 = (c0 & 3) * 8;
  const int rB1 = c1 >> 2, oB1 = (c1 & 3) * 8;

  // A staging unit (f32 path): 16 floats per thread
  const int rowA = tid >> 1;
  const int halfA = (tid & 1) * 16;

  for (int k0 = 0; k0 < 256; k0 += 32) {
    // --- B tiles via async global->LDS (bf16, 16B chunks) ---
    gll16(Wth + (size_t)(n0 + rB0) * 256 + k0 + oB0, &Bsh[c0 * 8]);
    gll16(Wth + (size_t)(n0 + rB1) * 256 + k0 + oB1, &Bsh[c1 * 8]);
    gll16(Wtl + (size_t)(n0 + rB0) * 256 + k0 + oB0, &Bsl[c0 * 8]);
    gll16(Wtl + (size_t)(n0 + rB1) * 256 + k0 + oB1, &Bsl[c1 * 8]);

    // --- A tile ---
    if (ABF16) {
      const bf16* Ab = (const bf16*)Aptr;
      gll16(Ab + (size_t)(m0 + rB0) * 256 + k0 + oB0, &Ash[c0 * 8]);
      gll16(Ab + (size_t)(m0 + rB1) * 256 + k0 + oB1, &Ash[c1 * 8]);
    } else {
      const float* Af = (const float*)Aptr;
      const float* src = Af + (size_t)(m0 + rowA) * 256 + k0 + halfA;
      float4 f0 = *(const float4*)(src);
      float4 f1 = *(const float4*)(src + 4);
      float4 f2 = *(const float4*)(src + 8);
      float4 f3 = *(const float4*)(src + 12);
      bf16x8 h0, l0, h1, l1;
      const float fa[16] = {f0.x, f0.y, f0.z, f0.w, f1.x, f1.y, f1.z, f1.w,
                            f2.x, f2.y, f2.z, f2.w, f3.x, f3.y, f3.z, f3.w};
#pragma unroll
      for (int j = 0; j < 8; ++j) {
        bf16 h = (bf16)fa[j];
        h0[j] = h;
        l0[j] = (bf16)(fa[j] - (float)h);
      }
#pragma unroll
      for (int j = 0; j < 8; ++j) {
        bf16 h = (bf16)fa[8 + j];
        h1[j] = h;
        l1[j] = (bf16)(fa[8 + j] - (float)h);
      }
      const int o = rowA * 32 + halfA;
      *(bf16x8*)&Ash[o] = h0;
      *(bf16x8*)&Ash[o + 8] = h1;
      *(bf16x8*)&Asl[o] = l0;
      *(bf16x8*)&Asl[o + 8] = l1;
    }
    __syncthreads();

    bf16x8 avh[4], bvh[4], bvl[4];
#pragma unroll
    for (int t = 0; t < 4; ++t)
      avh[t] = *(const bf16x8*)&Ash[(mw + t * 16 + lm) * 32 + lq * 8];
#pragma unroll
    for (int t = 0; t < 4; ++t) {
      bvh[t] = *(const bf16x8*)&Bsh[(nw + t * 16 + lm) * 32 + lq * 8];
      bvl[t] = *(const bf16x8*)&Bsl[(nw + t * 16 + lm) * 32 + lq * 8];
    }
#pragma unroll
    for (int i = 0; i < 4; ++i)
#pragma unroll
      for (int j = 0; j < 4; ++j) {
        acc[i][j] = __builtin_amdgcn_mfma_f32_16x16x32_bf16(avh[i], bvh[j], acc[i][j], 0, 0, 0);
        acc[i][j] = __builtin_amdgcn_mfma_f32_16x16x32_bf16(avh[i], bvl[j], acc[i][j], 0, 0, 0);
      }
    if (!ABF16) {
      bf16x8 avl[4];
#pragma unroll
      for (int t = 0; t < 4; ++t)
        avl[t] = *(const bf16x8*)&Asl[(mw + t * 16 + lm) * 32 + lq * 8];
#pragma unroll
      for (int i = 0; i < 4; ++i)
#pragma unroll
        for (int j = 0; j < 4; ++j)
          acc[i][j] = __builtin_amdgcn_mfma_f32_16x16x32_bf16(avl[i], bvh[j], acc[i][j], 0, 0, 0);
    }
    __syncthreads();
  }

  // Epilogue. C layout: col = lane&15, row = (lane>>4)*4 + reg.
#pragma unroll
  for (int i = 0; i < 4; ++i) {
#pragma unroll
    for (int j = 0; j < 4; ++j) {
      const int n_g = n0 + nw + j * 16 + lm;
      const bool hi = (n_g >= 256);
      const float* bp = hi ? bias1 : bias0;
      const int nc = n_g & 255;
      const float bval = bp[nc];
#pragma unroll
      for (int r = 0; r < 4; ++r) {
        const int m_g = m0 + mw + i * 16 + lq * 4 + r;
        const float v = acc[i][j][r] + bval;
        if (OUTF32) {
          float* op = hi ? (float*)out1 : (float*)out0;
          op[(size_t)m_g * 256 + nc] = v;
        } else {
          bf16* op = hi ? (bf16*)out1 : (bf16*)out0;
          op[(size_t)m_g * 256 + nc] = (bf16)v;
        }
      }
    }
  }
}

// ---------------------------------------------------------------------------
// Windowed attention (8x8 windows, hd=32). Block = (window) x (4-head group).
// 4 waves; wave = local head. Q/K/V staged 64 tok x 128 ch bf16 in LDS.
// S = Q K^T via MFMA, register softmax, P->LDS (XOR swizzle), O = P V via MFMA.
// ---------------------------------------------------------------------------
__global__ __launch_bounds__(256) void k_attn(
    const bf16* __restrict__ qp, const bf16* __restrict__ kp,
    const bf16* __restrict__ vp, bf16* __restrict__ ao) {
  __shared__ __align__(16) bf16 smem[3 * 64 * 136];  // 52224 B
  bf16* Qs = smem;                 // [64][136]
  bf16* Ks = smem + 64 * 136;
  bf16* Vs = smem + 2 * 64 * 136;
  bf16* Ps = smem;                 // 4 x [64][64] = 16384 elems (aliases Qs+Ks, freed)
  bf16* Os = Vs;                   // [64][136] (aliases Vs, freed)

  const int tid = threadIdx.x;
  const int lane = tid & 63;
  const int hl = tid >> 6;
  const int bw = blockIdx.x;
  const int b = bw >> 8;
  const int w = bw & 255;
  const int wy = w >> 4, wx = w & 15;
  const int ch0 = blockIdx.y * 128;

#pragma unroll
  for (int i = 0; i < 4; ++i) {
    const int c = i * 256 + tid;
    const int t = c >> 4;
    const int off = (c & 15) * 8;
    const int ty = t >> 3, tx = t & 7;
    const size_t gr = ((size_t)(b * 128 + wy * 8 + ty)) * 128 + wx * 8 + tx;
    const size_t gi = gr * 256 + ch0 + off;
    const int li = t * 136 + off;
    *(uint4*)&Qs[li] = *(const uint4*)&qp[gi];
    *(uint4*)&Ks[li] = *(const uint4*)&kp[gi];
    *(uint4*)&Vs[li] = *(const uint4*)&vp[gi];
  }
  __syncthreads();

  const int chh = hl * 32;
  const int lm = lane & 15;
  const int lq = lane >> 4;

  bf16x8 qa[4], kb[4];
#pragma unroll
  for (int t = 0; t < 4; ++t)
    qa[t] = *(const bf16x8*)&Qs[(t * 16 + lm) * 136 + chh + lq * 8];
#pragma unroll
  for (int t = 0; t < 4; ++t)
    kb[t] = *(const bf16x8*)&Ks[(t * 16 + lm) * 136 + chh + lq * 8];

  f32x4 s[4][4];
#pragma unroll
  for (int i = 0; i < 4; ++i)
#pragma unroll
    for (int j = 0; j < 4; ++j) s[i][j] = (f32x4)0.0f;
#pragma unroll
  for (int i = 0; i < 4; ++i)
#pragma unroll
    for (int j = 0; j < 4; ++j)
      s[i][j] = __builtin_amdgcn_mfma_f32_16x16x32_bf16(qa[i], kb[j], s[i][j], 0, 0, 0);

  const float scale = 0.17677669529663687f;  // 1/sqrt(32)
  float rl[4][4];
#pragma unroll
  for (int mt = 0; mt < 4; ++mt) {
#pragma unroll
    for (int r = 0; r < 4; ++r) {
      float mx = fmaxf(fmaxf(s[mt][0][r], s[mt][1][r]), fmaxf(s[mt][2][r], s[mt][3][r]));
      mx = fmaxf(mx, __shfl_xor(mx, 1));
      mx = fmaxf(mx, __shfl_xor(mx, 2));
      mx = fmaxf(mx, __shfl_xor(mx, 4));
      mx = fmaxf(mx, __shfl_xor(mx, 8));
      float sum = 0.f;
#pragma unroll
      for (int nt = 0; nt < 4; ++nt) {
        const float p = __expf((s[mt][nt][r] - mx) * scale);
        s[mt][nt][r] = p;
        sum += p;
      }
      sum += __shfl_xor(sum, 1);
      sum += __shfl_xor(sum, 2);
      sum += __shfl_xor(sum, 4);
      sum += __shfl_xor(sum, 8);
      rl[mt][r] = 1.0f / sum;
    }
  }

  __syncthreads();  // all waves done reading Qs/Ks

  bf16* Ph = Ps + hl * 4096;
#pragma unroll
  for (int mt = 0; mt < 4; ++mt)
#pragma unroll
    for (int nt = 0; nt < 4; ++nt)
#pragma unroll
      for (int r = 0; r < 4; ++r) {
        const int qrow = mt * 16 + lq * 4 + r;
        const int kcol = nt * 16 + lm;
        Ph[qrow * 64 + (((kcol >> 3) ^ (qrow & 7)) << 3) + (kcol & 7)] = (bf16)s[mt][nt][r];
      }

  f32x4 o[4][2];
#pragma unroll
  for (int i = 0; i < 4; ++i) { o[i][0] = (f32x4)0.0f; o[i][1] = (f32x4)0.0f; }
#pragma unroll
  for (int ks = 0; ks < 2; ++ks) {
    bf16x8 pa[4];
#pragma unroll
    for (int mt = 0; mt < 4; ++mt) {
      const int qrow = mt * 16 + lm;
      const int g = ks * 4 + lq;
      pa[mt] = *(const bf16x8*)&Ph[qrow * 64 + ((g ^ (qrow & 7)) << 3)];
    }
    bf16x8 vbf[2];
#pragma unroll
    for (int ntd = 0; ntd < 2; ++ntd) {
      const int d = ntd * 16 + lm;
      bf16x8 tv;
#pragma unroll
      for (int j = 0; j < 8; ++j)
        tv[j] = Vs[(ks * 32 + lq * 8 + j) * 136 + chh + d];
      vbf[ntd] = tv;
    }
#pragma unroll
    for (int mt = 0; mt < 4; ++mt)
#pragma unroll
      for (int ntd = 0; ntd < 2; ++ntd)
        o[mt][ntd] = __builtin_amdgcn_mfma_f32_16x16x32_bf16(pa[mt], vbf[ntd], o[mt][ntd], 0, 0, 0);
  }

  __syncthreads();  // all waves done reading Vs

#pragma unroll
  for (int mt = 0; mt < 4; ++mt)
#pragma unroll
    for (int ntd = 0; ntd < 2; ++ntd)
#pragma unroll
      for (int r = 0; r < 4; ++r) {
        const int qrow = mt * 16 + lq * 4 + r;
        const int d = ntd * 16 + lm;
        Os[qrow * 136 + chh + d] = (bf16)(o[mt][ntd][r] * rl[mt][r]);
      }
  __syncthreads();

#pragma unroll
  for (int i = 0; i < 4; ++i) {
    const int c = i * 256 + tid;
    const int t = c >> 4;
    const int off = (c & 15) * 8;
    const int ty = t >> 3, tx = t & 7;
    const size_t gr = ((size_t)(b * 128 + wy * 8 + ty)) * 128 + wx * 8 + tx;
    *(uint4*)&ao[gr * 256 + ch0 + off] = *(const uint4*)&Os[t * 136 + off];
  }
}

// ---------------------------------------------------------------------------
extern "C" void kernel_launch(void* const* d_in, const int* in_sizes, int n_in,
                              void* d_out, int out_size, void* d_ws, size_t ws_size,
                              hipStream_t stream) {
  const float* q  = (const float*)d_in[0];
  const float* kv = (const float*)d_in[1];
  const float* Wq = (const float*)d_in[2];
  const float* bq = (const float*)d_in[3];
  const float* Wk = (const float*)d_in[4];
  const float* bk = (const float*)d_in[5];
  const float* Wv = (const float*)d_in[6];
  const float* bv = (const float*)d_in[7];
  const float* Wo = (const float*)d_in[8];
  const float* bo = (const float*)d_in[9];
  float* out = (float*)d_out;

  char* ws = (char*)d_ws;
  bf16* wtq_h  = (bf16*)(ws + 0);        // 131072 B
  bf16* wtq_l  = (bf16*)(ws + 131072);
  bf16* wtkv_h = (bf16*)(ws + 262144);   // 262144 B
  bf16* wtkv_l = (bf16*)(ws + 524288);
  bf16* wto_h  = (bf16*)(ws + 786432);
  bf16* wto_l  = (bf16*)(ws + 917504);
  const size_t PLANE = (size_t)65536 * 256 * 2;  // 33554432 B (bf16 plane)
  bf16* qp = (bf16*)(ws + 1048576);
  bf16* kp = (bf16*)(ws + 1048576 + PLANE);
  bf16* vp = (bf16*)(ws + 1048576 + 2 * PLANE);
  bf16* ao = (bf16*)(ws + 1048576 + 3 * PLANE);
  if (ws_size < 1048576 + 4 * PLANE) return;  // ~135.3 MB needed

  k_prep<<<dim3(256, 4), 256, 0, stream>>>(Wq, Wk, Wv, Wo, wtq_h, wtq_l,
                                           wtkv_h, wtkv_l, wto_h, wto_l);
  // q projection (N=256)
  k_gemm3<false, false><<<dim3(512, 2), 256, 0, stream>>>(
      (const void*)q, wtq_h, wtq_l, bq, bq, (void*)qp, (void*)qp);
  // fused k+v projection (N=512, [Wk|Wv])
  k_gemm3<false, false><<<dim3(512, 4), 256, 0, stream>>>(
      (const void*)kv, wtkv_h, wtkv_l, bk, bv, (void*)kp, (void*)vp);
  // windowed attention
  k_attn<<<dim3(1024, 2), 256, 0, stream>>>(qp, kp, vp, ao);
  // output projection (bf16 A, f32 out)
  k_gemm3<true, true><<<dim3(512, 2), 256, 0, stream>>>(
      (const void*)ao, wto_h, wto_l, bo, bo, (void*)out, (void*)out);
}